// Round 3
// baseline (504.331 us; speedup 1.0000x reference)
//
#include <hip/hip_runtime.h>
#include <stdint.h>

typedef unsigned short u16;
typedef __attribute__((ext_vector_type(8))) _Float16 h8;  // 8 x fp16 (4 VGPRs)
typedef __attribute__((ext_vector_type(4))) float f4;     // 4 x f32 accumulator

#define B_ 2
#define SQ_ 2048
#define SK_ 2048
#define D_ 1024
#define H_ 16
#define DK_ 64

__device__ __forceinline__ u16 f2h(float f) {             // fp32 -> fp16 RNE
  union { _Float16 h; u16 u; } v; v.h = (_Float16)f; return v.u;
}
__device__ __forceinline__ float h2f(u16 b) {
  union { u16 u; _Float16 h; } v; v.u = b; return (float)v.h;
}

typedef const void __attribute__((address_space(1)))* gas1;
typedef void __attribute__((address_space(3)))* las3;
__device__ __forceinline__ void gld16(const void* g, void* l) {
  // async global->LDS, 16B per lane; LDS dest = wave-uniform base + lane*16
  __builtin_amdgcn_global_load_lds((gas1)g, (las3)l, 16, 0, 0);
}

// ---------------------------------------------------------------- merged casts
// z 0..2: X arrays (4M elems, 2048 blocks); z 3..6: W arrays (1M elems, 512 blocks)
__global__ void rma_cast(const float* __restrict__ xq, const float* __restrict__ xv,
                         const float* __restrict__ xr, const float* __restrict__ w0,
                         const float* __restrict__ w1, const float* __restrict__ w2,
                         const float* __restrict__ w3, u16* __restrict__ oq,
                         u16* __restrict__ ov, u16* __restrict__ orr,
                         u16* __restrict__ o0, u16* __restrict__ o1,
                         u16* __restrict__ o2, u16* __restrict__ o3) {
  const int z = blockIdx.z;
  if (z >= 3 && blockIdx.x >= 512) return;
  const float* src;
  u16* dst;
  switch (z) {
    case 0: src = xq; dst = oq; break;
    case 1: src = xv; dst = ov; break;
    case 2: src = xr; dst = orr; break;
    case 3: src = w0; dst = o0; break;
    case 4: src = w1; dst = o1; break;
    case 5: src = w2; dst = o2; break;
    default: src = w3; dst = o3; break;
  }
  int i = (blockIdx.x * 256 + threadIdx.x) * 8;
  float4 a = *(const float4*)(src + i);
  float4 b = *(const float4*)(src + i + 4);
  alignas(16) u16 t[8] = {f2h(a.x), f2h(a.y), f2h(a.z), f2h(a.w),
                          f2h(b.x), f2h(b.y), f2h(b.z), f2h(b.w)};
  *(int4*)(dst + i) = *(int4*)t;
}

// ---------------------------------------------------------------- GEMM core 128x128
__device__ __forceinline__ void gemm_mainloop(
    const u16* __restrict__ A, const u16* __restrict__ Bw, int K,
    u16* As, u16* Bs, int m0, int n0, f4 (&acc)[4][4]) {
  const int tid = threadIdx.x;
  const int w = tid >> 6, lane = tid & 63;
  const int quad = lane >> 4, ln = lane & 15;
  const int wm = (w >> 1) * 64, wn = (w & 1) * 64;
  const int c0 = tid, c1 = tid + 256;   // 16B chunk ids; row=c>>2, k8=(c&3)*8
  const u16* a0 = A + (size_t)(m0 + (c0 >> 2)) * K + (c0 & 3) * 8;
  const u16* a1 = A + (size_t)(m0 + (c1 >> 2)) * K + (c1 & 3) * 8;
  const u16* b0 = Bw + (size_t)(n0 + (c0 >> 2)) * K + (c0 & 3) * 8;
  const u16* b1 = Bw + (size_t)(n0 + (c1 >> 2)) * K + (c1 & 3) * 8;
  u16* As0 = As + (0 + w * 64) * 8;     // wave-uniform LDS bases
  u16* As1 = As + (256 + w * 64) * 8;
  u16* Bs0 = Bs + (0 + w * 64) * 8;
  u16* Bs1 = Bs + (256 + w * 64) * 8;
  for (int kt = 0; kt < K; kt += 32) {
    gld16(a0 + kt, As0);
    gld16(a1 + kt, As1);
    gld16(b0 + kt, Bs0);
    gld16(b1 + kt, Bs1);
    __syncthreads();
    h8 af[4], bf[4];
#pragma unroll
    for (int i = 0; i < 4; i++)
      af[i] = *(const h8*)&As[(wm + i * 16 + ln) * 32 + quad * 8];
#pragma unroll
    for (int i = 0; i < 4; i++)
      bf[i] = *(const h8*)&Bs[(wn + i * 16 + ln) * 32 + quad * 8];
#pragma unroll
    for (int i = 0; i < 4; i++)
#pragma unroll
      for (int j = 0; j < 4; j++)
        acc[i][j] = __builtin_amdgcn_mfma_f32_16x16x32_f16(af[i], bf[j], acc[i][j], 0, 0, 0);
    __syncthreads();
  }
}

// ---------------------------------------------------------------- GEMM core 64x128
__device__ __forceinline__ void gemm_mainloop64(
    const u16* __restrict__ A, const u16* __restrict__ Bw, int K,
    u16* As, u16* Bs, int m0, int n0, f4 (&acc)[2][4]) {
  const int tid = threadIdx.x;
  const int w = tid >> 6, lane = tid & 63;
  const int quad = lane >> 4, ln = lane & 15;
  const int wm = (w >> 1) * 32, wn = (w & 1) * 64;
  const u16* a0 = A + (size_t)(m0 + (tid >> 2)) * K + (tid & 3) * 8;
  const u16* b0 = Bw + (size_t)(n0 + (tid >> 2)) * K + (tid & 3) * 8;
  const u16* b1 = Bw + (size_t)(n0 + ((tid + 256) >> 2)) * K + (tid & 3) * 8;
  u16* As0 = As + (w * 64) * 8;
  u16* Bs0 = Bs + (w * 64) * 8;
  u16* Bs1 = Bs + (256 + w * 64) * 8;
  for (int kt = 0; kt < K; kt += 32) {
    gld16(a0 + kt, As0);
    gld16(b0 + kt, Bs0);
    gld16(b1 + kt, Bs1);
    __syncthreads();
    h8 af[2], bf[4];
#pragma unroll
    for (int i = 0; i < 2; i++)
      af[i] = *(const h8*)&As[(wm + i * 16 + ln) * 32 + quad * 8];
#pragma unroll
    for (int j = 0; j < 4; j++)
      bf[j] = *(const h8*)&Bs[(wn + j * 16 + ln) * 32 + quad * 8];
#pragma unroll
    for (int i = 0; i < 2; i++)
#pragma unroll
      for (int j = 0; j < 4; j++)
        acc[i][j] = __builtin_amdgcn_mfma_f32_16x16x32_f16(af[i], bf[j], acc[i][j], 0, 0, 0);
    __syncthreads();
  }
}

// fused Q/V/R projections; z selects operand set + epilogue layout
// z==0 -> Qb (B,H,SQ,DK) fp16 ; z==1 -> Vt (B,H,DK,SK) fp16 (transposed!) ; z==2 -> Rp f32
__global__ __launch_bounds__(256, 2)
void rma_proj_gemm(const u16* __restrict__ Xq, const u16* __restrict__ Xv,
                   const u16* __restrict__ Xr, const u16* __restrict__ Wq,
                   const u16* __restrict__ Wv, const u16* __restrict__ Wr,
                   const float* __restrict__ bq, const float* __restrict__ bv,
                   const float* __restrict__ br, u16* __restrict__ Qb,
                   u16* __restrict__ Vt, float* __restrict__ Rp) {
  const int z = blockIdx.z;
  const u16* A = z == 0 ? Xq : (z == 1 ? Xv : Xr);
  const u16* Bw = z == 0 ? Wq : (z == 1 ? Wv : Wr);
  const float* bias = z == 0 ? bq : (z == 1 ? bv : br);
  __shared__ u16 As[128 * 32];
  __shared__ u16 Bs[128 * 32];
  const int m0 = blockIdx.x * 128, n0 = blockIdx.y * 128;
  f4 acc[4][4] = {};
  gemm_mainloop(A, Bw, D_, As, Bs, m0, n0, acc);
  const int tid = threadIdx.x;
  const int w = tid >> 6, lane = tid & 63;
  const int quad = lane >> 4, ln = lane & 15;
  const int wm = (w >> 1) * 64, wn = (w & 1) * 64;
#pragma unroll
  for (int i = 0; i < 4; i++)
#pragma unroll
    for (int j = 0; j < 4; j++) {
      const int colg = n0 + wn + j * 16 + ln;
      const float bb = bias[colg];
      const int h = colg >> 6, d = colg & 63;
      const int row4 = m0 + wm + i * 16 + quad * 4;  // 4 consecutive rows
      const int b = row4 >> 11, s = row4 & 2047;
      if (z == 1) {
        // V^T: (bh, d, s) — 4 consecutive s, packed 8B store
        unsigned lo = (unsigned)f2h(acc[i][j][0] + bb) | ((unsigned)f2h(acc[i][j][1] + bb) << 16);
        unsigned hi = (unsigned)f2h(acc[i][j][2] + bb) | ((unsigned)f2h(acc[i][j][3] + bb) << 16);
        uint2 pk; pk.x = lo; pk.y = hi;
        *(uint2*)&Vt[((size_t)((b * H_ + h) * DK_ + d)) * SK_ + s] = pk;
      } else {
#pragma unroll
        for (int r = 0; r < 4; r++) {
          const float v = acc[i][j][r] + bb;
          const size_t idx = ((size_t)(b * H_ + h) * SK_ + (s + r)) * DK_ + d;
          if (z == 2) Rp[idx] = v;
          else Qb[idx] = f2h(v);
        }
      }
    }
}

__global__ __launch_bounds__(256, 2)
void rma_final_gemm(const u16* __restrict__ Og, const u16* __restrict__ Wo,
                    const float* __restrict__ bo, float* __restrict__ out) {
  __shared__ u16 As[64 * 32];
  __shared__ u16 Bs[128 * 32];
  const int m0 = blockIdx.x * 64, n0 = blockIdx.y * 128;
  f4 acc[2][4] = {};
  gemm_mainloop64(Og, Wo, D_, As, Bs, m0, n0, acc);
  const int tid = threadIdx.x;
  const int w = tid >> 6, lane = tid & 63;
  const int quad = lane >> 4, ln = lane & 15;
  const int wm = (w >> 1) * 32, wn = (w & 1) * 64;
#pragma unroll
  for (int i = 0; i < 2; i++)
#pragma unroll
    for (int j = 0; j < 4; j++) {
      const int colg = n0 + wn + j * 16 + ln;
      const float bb = bo[colg];
#pragma unroll
      for (int r = 0; r < 4; r++) {
        const int rowg = m0 + wm + i * 16 + quad * 4 + r;
        out[(size_t)rowg * D_ + colg] = acc[i][j][r] + bb;
      }
    }
}

// ---------------------------------------------------------------- recurrence
// h_t = tanh(h_{t-1}*wsum + r_t), per (b,h,d) channel; wsum = sum_k W_h[h,d,k]
__global__ void rma_recurrence(const float* __restrict__ Rp, const float* __restrict__ Wh,
                               u16* __restrict__ Hst) {
  const int idx = blockIdx.x * 64 + threadIdx.x;   // 0..2047
  const int d = idx & 63, h = (idx >> 6) & 15, b = idx >> 10;
  const float* wr = Wh + (h * 64 + d) * 64;
  float ws = 0.f;
#pragma unroll 8
  for (int k = 0; k < 64; k++) ws += wr[k];
  const float C2 = 2.885390081777927f;  // 2*log2(e): tanh(y)=1-2/(2^(C2*y)+1)
  const float wc = ws * C2;
  const size_t base = (size_t)(b * H_ + h) * SK_ * DK_ + d;
  const float* r = Rp + base;
  u16* o = Hst + base;
  float hs = 0.f;
#pragma unroll 4
  for (int t = 0; t < SK_; t++) {
    float rc = r[(size_t)t * DK_] * C2;           // off-chain load+mul
    float x = __builtin_fmaf(hs, wc, rc);
    float e = exp2f(x);                           // v_exp_f32
    float inv = __builtin_amdgcn_rcpf(e + 1.0f);  // v_rcp_f32
    hs = __builtin_fmaf(-2.0f, inv, 1.0f);
    o[(size_t)t * DK_] = f2h(hs);
  }
}

// ---------------------------------------------------------------- flash attention
// Transposed-S design: S^T = K·Q^T so q = lane&15 per lane; per-lane softmax
// state; wave-private P LDS round-trip (no __syncthreads in k-loop); all MFMA
// operands loaded directly from global (L1-shared across the 4 waves).
// Block = 4 waves x 32 q = 128 q rows; grid (SQ/128, B*H).
__global__ __launch_bounds__(256, 2)
void rma_flash(const u16* __restrict__ Qb, const u16* __restrict__ Hst,
               const u16* __restrict__ Vt, u16* __restrict__ Og) {
  __shared__ u16 Ps[4][32 * 72];   // per-wave P scratch [q_local][k_local], stride 72
  const int tid = threadIdx.x;
  const int w = tid >> 6, lane = tid & 63;
  const int quad = lane >> 4, ln = lane & 15;
  const int bh = blockIdx.y;
  const int q0 = blockIdx.x * 128 + w * 32;
  const float scale2 = 0.18033688011112042f;  // log2(e)/sqrt(DK)
  const u16* Qg = Qb + (size_t)bh * SQ_ * DK_;
  const u16* Kg = Hst + (size_t)bh * SK_ * DK_;
  const u16* Vg = Vt + (size_t)bh * DK_ * SK_;
  u16* Pw = Ps[w];
  h8 qf[2][2];
#pragma unroll
  for (int qt = 0; qt < 2; qt++)
#pragma unroll
    for (int c = 0; c < 2; c++)
      qf[qt][c] = *(const h8*)&Qg[(size_t)(q0 + qt * 16 + ln) * DK_ + c * 32 + quad * 8];
  f4 o[4][2] = {};                 // O^T[d=dt*16+quad*4+r][q=qt*16+ln]
  float mx[2] = {-3e38f, -3e38f};  // raw running max (per-lane q)
  float ms[2] = {-3e38f, -3e38f};  // scaled-domain max
  float l[2] = {0.f, 0.f};

  for (int kt = 0; kt < SK_; kt += 64) {
    // S^T tiles: st[m][qt] holds S[k=kt+16m+quad*4+r][q=qt*16+ln]
    f4 st[4][2];
#pragma unroll
    for (int m = 0; m < 4; m++) {
      h8 k0 = *(const h8*)&Kg[(size_t)(kt + m * 16 + ln) * DK_ + quad * 8];
      h8 k1 = *(const h8*)&Kg[(size_t)(kt + m * 16 + ln) * DK_ + 32 + quad * 8];
#pragma unroll
      for (int qt = 0; qt < 2; qt++) {
        f4 t = {0.f, 0.f, 0.f, 0.f};
        t = __builtin_amdgcn_mfma_f32_16x16x32_f16(k0, qf[qt][0], t, 0, 0, 0);
        t = __builtin_amdgcn_mfma_f32_16x16x32_f16(k1, qf[qt][1], t, 0, 0, 0);
        st[m][qt] = t;
      }
    }
    // prefetch V^T fragments (consumed after softmax — loads fly over it)
    h8 vf[4][2];
#pragma unroll
    for (int dt = 0; dt < 4; dt++)
#pragma unroll
      for (int c = 0; c < 2; c++)
        vf[dt][c] = *(const h8*)&Vg[(size_t)(dt * 16 + ln) * SK_ + kt + c * 32 + quad * 8];
    // online softmax: per-lane rows, in-register + 2 cross-quad butterflies
#pragma unroll
    for (int qt = 0; qt < 2; qt++) {
      float rmax = st[0][qt][0];
#pragma unroll
      for (int m = 0; m < 4; m++)
#pragma unroll
        for (int r = 0; r < 4; r++) rmax = fmaxf(rmax, st[m][qt][r]);
      rmax = fmaxf(rmax, __shfl_xor(rmax, 16));
      rmax = fmaxf(rmax, __shfl_xor(rmax, 32));
      const float mxn = fmaxf(mx[qt], rmax);
      const float msn = mxn * scale2;
      float sum = 0.f;
#pragma unroll
      for (int m = 0; m < 4; m++) {
        const float p0 = exp2f(__builtin_fmaf(st[m][qt][0], scale2, -msn));
        const float p1 = exp2f(__builtin_fmaf(st[m][qt][1], scale2, -msn));
        const float p2 = exp2f(__builtin_fmaf(st[m][qt][2], scale2, -msn));
        const float p3 = exp2f(__builtin_fmaf(st[m][qt][3], scale2, -msn));
        sum += (p0 + p1) + (p2 + p3);
        uint2 pk;
        pk.x = (unsigned)f2h(p0) | ((unsigned)f2h(p1) << 16);
        pk.y = (unsigned)f2h(p2) | ((unsigned)f2h(p3) << 16);
        *(uint2*)&Pw[(qt * 16 + ln) * 72 + m * 16 + quad * 4] = pk;
      }
      sum += __shfl_xor(sum, 16);
      sum += __shfl_xor(sum, 32);
      if (__any(rmax > mx[qt])) {
        const float alpha = exp2f(ms[qt] - msn);
        l[qt] = __builtin_fmaf(l[qt], alpha, sum);
#pragma unroll
        for (int dt = 0; dt < 4; dt++)
#pragma unroll
          for (int r = 0; r < 4; r++) o[dt][qt][r] *= alpha;
      } else {
        l[qt] += sum;
      }
      mx[qt] = mxn;
      ms[qt] = msn;
    }
    // wave-private write->read: LDS is in-order per wave; fence the compiler
    asm volatile("" ::: "memory");
    __builtin_amdgcn_sched_barrier(0);
    // O^T += V^T · P^T
#pragma unroll
    for (int c = 0; c < 2; c++) {
      h8 pb0 = *(const h8*)&Pw[(0 + ln) * 72 + c * 32 + quad * 8];
      h8 pb1 = *(const h8*)&Pw[(16 + ln) * 72 + c * 32 + quad * 8];
#pragma unroll
      for (int dt = 0; dt < 4; dt++) {
        o[dt][0] = __builtin_amdgcn_mfma_f32_16x16x32_f16(vf[dt][c], pb0, o[dt][0], 0, 0, 0);
        o[dt][1] = __builtin_amdgcn_mfma_f32_16x16x32_f16(vf[dt][c], pb1, o[dt][1], 0, 0, 0);
      }
    }
  }
  // epilogue: O^T/l -> Og[b][q][h*64+d], packed 8B stores
  const int b = bh >> 4, h = bh & 15;
#pragma unroll
  for (int qt = 0; qt < 2; qt++) {
    const float linv = __builtin_amdgcn_rcpf(l[qt]);
    const int q = q0 + qt * 16 + ln;
#pragma unroll
    for (int dt = 0; dt < 4; dt++) {
      uint2 pk;
      pk.x = (unsigned)f2h(o[dt][qt][0] * linv) | ((unsigned)f2h(o[dt][qt][1] * linv) << 16);
      pk.y = (unsigned)f2h(o[dt][qt][2] * linv) | ((unsigned)f2h(o[dt][qt][3] * linv) << 16);
      *(uint2*)&Og[((size_t)b * SQ_ + q) * D_ + h * DK_ + dt * 16 + quad * 4] = pk;
    }
  }
}

// ---------------------------------------------------------------- launch
extern "C" void kernel_launch(void* const* d_in, const int* in_sizes, int n_in,
                              void* d_out, int out_size, void* d_ws, size_t ws_size,
                              hipStream_t stream) {
  const float* query = (const float*)d_in[0];
  // d_in[1] = key : unused by the reference forward
  const float* value = (const float*)d_in[2];
  const float* R = (const float*)d_in[3];
  const float* Wq = (const float*)d_in[4];
  const float* bq = (const float*)d_in[5];
  const float* Wv = (const float*)d_in[6];
  const float* bv = (const float*)d_in[7];
  const float* Wr = (const float*)d_in[8];
  const float* br = (const float*)d_in[9];
  const float* W_h = (const float*)d_in[10];
  const float* Wo = (const float*)d_in[11];
  const float* bo = (const float*)d_in[12];
  float* out = (float*)d_out;

  char* ws = (char*)d_ws;
  const size_t MB = 1 << 20;
  u16* Xq = (u16*)(ws + 0 * MB);     // 8MB fp16 query
  u16* Xv = (u16*)(ws + 8 * MB);     // 8MB fp16 value
  u16* Xr = (u16*)(ws + 16 * MB);    // 8MB fp16 R
  u16* Wqb = (u16*)(ws + 24 * MB);   // 2MB
  u16* Wvb = (u16*)(ws + 26 * MB);   // 2MB
  u16* Wrb = (u16*)(ws + 28 * MB);   // 2MB
  u16* Wob = (u16*)(ws + 30 * MB);   // 2MB
  u16* Qb = (u16*)(ws + 32 * MB);    // 8MB fp16 (B,H,SQ,DK)
  u16* Vt = (u16*)(ws + 40 * MB);    // 8MB fp16 (B,H,DK,SK)  written directly by proj
  float* Rp = (float*)(ws + 48 * MB); // 16MB f32 (B,H,SK,DK)
  u16* Hs = (u16*)(ws + 64 * MB);    // 8MB fp16 (B,H,SK,DK)
  u16* Og = (u16*)(ws + 72 * MB);    // 8MB fp16 (B,SQ,D)  -> total 80MB

  rma_cast<<<dim3(2048, 1, 7), 256, 0, stream>>>(query, value, R, Wq, Wv, Wr, Wo,
                                                 Xq, Xv, Xr, Wqb, Wvb, Wrb, Wob);
  rma_proj_gemm<<<dim3(32, 8, 3), 256, 0, stream>>>(Xq, Xv, Xr, Wqb, Wvb, Wrb,
                                                    bq, bv, br, Qb, Vt, Rp);
  rma_recurrence<<<dim3(32), 64, 0, stream>>>(Rp, W_h, Hs);
  rma_flash<<<dim3(16, 32), 256, 0, stream>>>(Qb, Hs, Vt, Og);
  rma_final_gemm<<<dim3(64, 8), 256, 0, stream>>>(Og, Wob, bo, out);
}

// Round 5
// 390.078 us; speedup vs baseline: 1.2929x; 1.2929x over previous
//
#include <hip/hip_runtime.h>
#include <stdint.h>

typedef unsigned short u16;
typedef __attribute__((ext_vector_type(8))) _Float16 h8;  // 8 x fp16 (4 VGPRs)
typedef __attribute__((ext_vector_type(4))) float f4;     // 4 x f32 accumulator

#define B_ 2
#define SQ_ 2048
#define SK_ 2048
#define D_ 1024
#define H_ 16
#define DK_ 64

__device__ __forceinline__ u16 f2h(float f) {             // fp32 -> fp16 RNE
  union { _Float16 h; u16 u; } v; v.h = (_Float16)f; return v.u;
}
__device__ __forceinline__ float h2f(u16 b) {
  union { u16 u; _Float16 h; } v; v.u = b; return (float)v.h;
}

typedef const void __attribute__((address_space(1)))* gas1;
typedef void __attribute__((address_space(3)))* las3;
__device__ __forceinline__ void gld16(const void* g, void* l) {
  // async global->LDS, 16B per lane; LDS dest = wave-uniform base + lane*16
  __builtin_amdgcn_global_load_lds((gas1)g, (las3)l, 16, 0, 0);
}

// ---------------------------------------------------------------- merged casts
// z 0..2: X arrays (4M elems, 2048 blocks); z 3..6: W arrays (1M elems, 512 blocks)
__global__ void rma_cast(const float* __restrict__ xq, const float* __restrict__ xv,
                         const float* __restrict__ xr, const float* __restrict__ w0,
                         const float* __restrict__ w1, const float* __restrict__ w2,
                         const float* __restrict__ w3, u16* __restrict__ oq,
                         u16* __restrict__ ov, u16* __restrict__ orr,
                         u16* __restrict__ o0, u16* __restrict__ o1,
                         u16* __restrict__ o2, u16* __restrict__ o3) {
  const int z = blockIdx.z;
  if (z >= 3 && blockIdx.x >= 512) return;
  const float* src;
  u16* dst;
  switch (z) {
    case 0: src = xq; dst = oq; break;
    case 1: src = xv; dst = ov; break;
    case 2: src = xr; dst = orr; break;
    case 3: src = w0; dst = o0; break;
    case 4: src = w1; dst = o1; break;
    case 5: src = w2; dst = o2; break;
    default: src = w3; dst = o3; break;
  }
  int i = (blockIdx.x * 256 + threadIdx.x) * 8;
  float4 a = *(const float4*)(src + i);
  float4 b = *(const float4*)(src + i + 4);
  alignas(16) u16 t[8] = {f2h(a.x), f2h(a.y), f2h(a.z), f2h(a.w),
                          f2h(b.x), f2h(b.y), f2h(b.z), f2h(b.w)};
  *(int4*)(dst + i) = *(int4*)t;
}

// ---------------------------------------------------------------- GEMM core 128x128
__device__ __forceinline__ void gemm_mainloop(
    const u16* __restrict__ A, const u16* __restrict__ Bw, int K,
    u16* As, u16* Bs, int m0, int n0, f4 (&acc)[4][4]) {
  const int tid = threadIdx.x;
  const int w = tid >> 6, lane = tid & 63;
  const int quad = lane >> 4, ln = lane & 15;
  const int wm = (w >> 1) * 64, wn = (w & 1) * 64;
  const int c0 = tid, c1 = tid + 256;   // 16B chunk ids; row=c>>2, k8=(c&3)*8
  const u16* a0 = A + (size_t)(m0 + (c0 >> 2)) * K + (c0 & 3) * 8;
  const u16* a1 = A + (size_t)(m0 + (c1 >> 2)) * K + (c1 & 3) * 8;
  const u16* b0 = Bw + (size_t)(n0 + (c0 >> 2)) * K + (c0 & 3) * 8;
  const u16* b1 = Bw + (size_t)(n0 + (c1 >> 2)) * K + (c1 & 3) * 8;
  u16* As0 = As + (0 + w * 64) * 8;     // wave-uniform LDS bases
  u16* As1 = As + (256 + w * 64) * 8;
  u16* Bs0 = Bs + (0 + w * 64) * 8;
  u16* Bs1 = Bs + (256 + w * 64) * 8;
  for (int kt = 0; kt < K; kt += 32) {
    gld16(a0 + kt, As0);
    gld16(a1 + kt, As1);
    gld16(b0 + kt, Bs0);
    gld16(b1 + kt, Bs1);
    __syncthreads();
    h8 af[4], bf[4];
#pragma unroll
    for (int i = 0; i < 4; i++)
      af[i] = *(const h8*)&As[(wm + i * 16 + ln) * 32 + quad * 8];
#pragma unroll
    for (int i = 0; i < 4; i++)
      bf[i] = *(const h8*)&Bs[(wn + i * 16 + ln) * 32 + quad * 8];
#pragma unroll
    for (int i = 0; i < 4; i++)
#pragma unroll
      for (int j = 0; j < 4; j++)
        acc[i][j] = __builtin_amdgcn_mfma_f32_16x16x32_f16(af[i], bf[j], acc[i][j], 0, 0, 0);
    __syncthreads();
  }
}

// ---------------------------------------------------------------- GEMM core 64x128
__device__ __forceinline__ void gemm_mainloop64(
    const u16* __restrict__ A, const u16* __restrict__ Bw, int K,
    u16* As, u16* Bs, int m0, int n0, f4 (&acc)[2][4]) {
  const int tid = threadIdx.x;
  const int w = tid >> 6, lane = tid & 63;
  const int quad = lane >> 4, ln = lane & 15;
  const int wm = (w >> 1) * 32, wn = (w & 1) * 64;
  const u16* a0 = A + (size_t)(m0 + (tid >> 2)) * K + (tid & 3) * 8;
  const u16* b0 = Bw + (size_t)(n0 + (tid >> 2)) * K + (tid & 3) * 8;
  const u16* b1 = Bw + (size_t)(n0 + ((tid + 256) >> 2)) * K + (tid & 3) * 8;
  u16* As0 = As + (w * 64) * 8;
  u16* Bs0 = Bs + (w * 64) * 8;
  u16* Bs1 = Bs + (256 + w * 64) * 8;
  for (int kt = 0; kt < K; kt += 32) {
    gld16(a0 + kt, As0);
    gld16(b0 + kt, Bs0);
    gld16(b1 + kt, Bs1);
    __syncthreads();
    h8 af[2], bf[4];
#pragma unroll
    for (int i = 0; i < 2; i++)
      af[i] = *(const h8*)&As[(wm + i * 16 + ln) * 32 + quad * 8];
#pragma unroll
    for (int j = 0; j < 4; j++)
      bf[j] = *(const h8*)&Bs[(wn + j * 16 + ln) * 32 + quad * 8];
#pragma unroll
    for (int i = 0; i < 2; i++)
#pragma unroll
      for (int j = 0; j < 4; j++)
        acc[i][j] = __builtin_amdgcn_mfma_f32_16x16x32_f16(af[i], bf[j], acc[i][j], 0, 0, 0);
    __syncthreads();
  }
}

// fused Q/V/R projections; z selects operand set + epilogue layout
// z==0 -> Qb (B,H,SQ,DK) fp16 ; z==1 -> Vt (B,H,DK,SK) fp16 (transposed!) ; z==2 -> Rp f32
__global__ __launch_bounds__(256, 2)
void rma_proj_gemm(const u16* __restrict__ Xq, const u16* __restrict__ Xv,
                   const u16* __restrict__ Xr, const u16* __restrict__ Wq,
                   const u16* __restrict__ Wv, const u16* __restrict__ Wr,
                   const float* __restrict__ bq, const float* __restrict__ bv,
                   const float* __restrict__ br, u16* __restrict__ Qb,
                   u16* __restrict__ Vt, float* __restrict__ Rp) {
  const int z = blockIdx.z;
  const u16* A = z == 0 ? Xq : (z == 1 ? Xv : Xr);
  const u16* Bw = z == 0 ? Wq : (z == 1 ? Wv : Wr);
  const float* bias = z == 0 ? bq : (z == 1 ? bv : br);
  __shared__ u16 As[128 * 32];
  __shared__ u16 Bs[128 * 32];
  const int m0 = blockIdx.x * 128, n0 = blockIdx.y * 128;
  f4 acc[4][4] = {};
  gemm_mainloop(A, Bw, D_, As, Bs, m0, n0, acc);
  const int tid = threadIdx.x;
  const int w = tid >> 6, lane = tid & 63;
  const int quad = lane >> 4, ln = lane & 15;
  const int wm = (w >> 1) * 64, wn = (w & 1) * 64;
#pragma unroll
  for (int i = 0; i < 4; i++)
#pragma unroll
    for (int j = 0; j < 4; j++) {
      const int colg = n0 + wn + j * 16 + ln;
      const float bb = bias[colg];
      const int h = colg >> 6, d = colg & 63;
      const int row4 = m0 + wm + i * 16 + quad * 4;  // 4 consecutive rows
      const int b = row4 >> 11, s = row4 & 2047;
      if (z == 1) {
        // V^T: (bh, d, s) — 4 consecutive s, packed 8B store
        unsigned lo = (unsigned)f2h(acc[i][j][0] + bb) | ((unsigned)f2h(acc[i][j][1] + bb) << 16);
        unsigned hi = (unsigned)f2h(acc[i][j][2] + bb) | ((unsigned)f2h(acc[i][j][3] + bb) << 16);
        uint2 pk; pk.x = lo; pk.y = hi;
        *(uint2*)&Vt[((size_t)((b * H_ + h) * DK_ + d)) * SK_ + s] = pk;
      } else {
#pragma unroll
        for (int r = 0; r < 4; r++) {
          const float v = acc[i][j][r] + bb;
          const size_t idx = ((size_t)(b * H_ + h) * SK_ + (s + r)) * DK_ + d;
          if (z == 2) Rp[idx] = v;
          else Qb[idx] = f2h(v);
        }
      }
    }
}

__global__ __launch_bounds__(256, 2)
void rma_final_gemm(const u16* __restrict__ Og, const u16* __restrict__ Wo,
                    const float* __restrict__ bo, float* __restrict__ out) {
  __shared__ u16 As[64 * 32];
  __shared__ u16 Bs[128 * 32];
  const int m0 = blockIdx.x * 64, n0 = blockIdx.y * 128;
  f4 acc[2][4] = {};
  gemm_mainloop64(Og, Wo, D_, As, Bs, m0, n0, acc);
  const int tid = threadIdx.x;
  const int w = tid >> 6, lane = tid & 63;
  const int quad = lane >> 4, ln = lane & 15;
  const int wm = (w >> 1) * 32, wn = (w & 1) * 64;
#pragma unroll
  for (int i = 0; i < 2; i++)
#pragma unroll
    for (int j = 0; j < 4; j++) {
      const int colg = n0 + wn + j * 16 + ln;
      const float bb = bo[colg];
#pragma unroll
      for (int r = 0; r < 4; r++) {
        const int rowg = m0 + wm + i * 16 + quad * 4 + r;
        out[(size_t)rowg * D_ + colg] = acc[i][j][r] + bb;
      }
    }
}

// ---------------------------------------------------------------- recurrence
// h_t = tanh(h_{t-1}*wsum + r_t) — EXACT sequential scan (chunk-parallel
// warmup is unsound: |w_rowsum|>1 channels are bistable, wrong-branch errors
// don't decay with warmup).  The chain is the floor (~2048 x 25cy = 21us);
// loads are chain-independent, so hide them with 32-deep register
// double-buffering.  One wave per (b,h): lanes = d, 256B coalesced per step.
#define RB_ 32
__global__ __launch_bounds__(64)
void rma_recurrence(const float* __restrict__ Rp, const float* __restrict__ Wh,
                    u16* __restrict__ Hst) {
  const int bh = blockIdx.x;          // 0..31
  const int d = threadIdx.x;          // 0..63
  const int h = bh & 15;
  const float* wr = Wh + (h * 64 + d) * 64;
  float ws = 0.f;
#pragma unroll
  for (int k = 0; k < 64; k += 4) {
    float4 wv = *(const float4*)(wr + k);
    ws += (wv.x + wv.y) + (wv.z + wv.w);
  }
  const float C2 = 2.885390081777927f;  // 2*log2(e): tanh(y)=1-2/(2^(C2*y)+1)
  const float wc = ws * C2;
  const size_t base = (size_t)bh * (SK_ * DK_) + d;
  const float* r = Rp + base;
  u16* o = Hst + base;
  float cur[RB_], nxt[RB_];
#pragma unroll
  for (int j = 0; j < RB_; j++) cur[j] = r[(size_t)j * DK_];
  float hs = 0.f;
  for (int t0 = 0; t0 < SK_; t0 += RB_) {
    const int tn = (t0 + RB_ < SK_) ? (t0 + RB_) : t0;  // dummy reload at end
#pragma unroll
    for (int j = 0; j < RB_; j++) nxt[j] = r[(size_t)(tn + j) * DK_];
#pragma unroll
    for (int j = 0; j < RB_; j++) {
      const float cc = cur[j] * C2;                 // off-chain scale
      float x = __builtin_fmaf(hs, wc, cc);
      float e = exp2f(x);                           // v_exp_f32
      float inv = __builtin_amdgcn_rcpf(e + 1.0f);  // v_rcp_f32
      hs = __builtin_fmaf(-2.0f, inv, 1.0f);
      o[(size_t)(t0 + j) * DK_] = f2h(hs);
    }
#pragma unroll
    for (int j = 0; j < RB_; j++) cur[j] = nxt[j];
  }
}

// ---------------------------------------------------------------- flash attention
// Transposed-S design: S^T = K·Q^T so q = lane&15 per lane; per-lane softmax
// state; wave-private P LDS round-trip (no __syncthreads in k-loop); all MFMA
// operands loaded directly from global (L1-shared across the 4 waves).
// Block = 4 waves x 32 q = 128 q rows; grid (SQ/128, B*H).
__global__ __launch_bounds__(256, 2)
void rma_flash(const u16* __restrict__ Qb, const u16* __restrict__ Hst,
               const u16* __restrict__ Vt, u16* __restrict__ Og) {
  __shared__ u16 Ps[4][32 * 72];   // per-wave P scratch [q_local][k_local], stride 72
  const int tid = threadIdx.x;
  const int w = tid >> 6, lane = tid & 63;
  const int quad = lane >> 4, ln = lane & 15;
  const int bh = blockIdx.y;
  const int q0 = blockIdx.x * 128 + w * 32;
  const float scale2 = 0.18033688011112042f;  // log2(e)/sqrt(DK)
  const u16* Qg = Qb + (size_t)bh * SQ_ * DK_;
  const u16* Kg = Hst + (size_t)bh * SK_ * DK_;
  const u16* Vg = Vt + (size_t)bh * DK_ * SK_;
  u16* Pw = Ps[w];
  h8 qf[2][2];
#pragma unroll
  for (int qt = 0; qt < 2; qt++)
#pragma unroll
    for (int c = 0; c < 2; c++)
      qf[qt][c] = *(const h8*)&Qg[(size_t)(q0 + qt * 16 + ln) * DK_ + c * 32 + quad * 8];
  f4 o[4][2] = {};                 // O^T[d=dt*16+quad*4+r][q=qt*16+ln]
  float mx[2] = {-3e38f, -3e38f};  // raw running max (per-lane q)
  float ms[2] = {-3e38f, -3e38f};  // scaled-domain max
  float l[2] = {0.f, 0.f};

  for (int kt = 0; kt < SK_; kt += 64) {
    // S^T tiles: st[m][qt] holds S[k=kt+16m+quad*4+r][q=qt*16+ln]
    f4 st[4][2];
#pragma unroll
    for (int m = 0; m < 4; m++) {
      h8 k0 = *(const h8*)&Kg[(size_t)(kt + m * 16 + ln) * DK_ + quad * 8];
      h8 k1 = *(const h8*)&Kg[(size_t)(kt + m * 16 + ln) * DK_ + 32 + quad * 8];
#pragma unroll
      for (int qt = 0; qt < 2; qt++) {
        f4 t = {0.f, 0.f, 0.f, 0.f};
        t = __builtin_amdgcn_mfma_f32_16x16x32_f16(k0, qf[qt][0], t, 0, 0, 0);
        t = __builtin_amdgcn_mfma_f32_16x16x32_f16(k1, qf[qt][1], t, 0, 0, 0);
        st[m][qt] = t;
      }
    }
    // prefetch V^T fragments (consumed after softmax — loads fly over it)
    h8 vf[4][2];
#pragma unroll
    for (int dt = 0; dt < 4; dt++)
#pragma unroll
      for (int c = 0; c < 2; c++)
        vf[dt][c] = *(const h8*)&Vg[(size_t)(dt * 16 + ln) * SK_ + kt + c * 32 + quad * 8];
    // online softmax: per-lane rows, in-register + 2 cross-quad butterflies
#pragma unroll
    for (int qt = 0; qt < 2; qt++) {
      float rmax = st[0][qt][0];
#pragma unroll
      for (int m = 0; m < 4; m++)
#pragma unroll
        for (int r = 0; r < 4; r++) rmax = fmaxf(rmax, st[m][qt][r]);
      rmax = fmaxf(rmax, __shfl_xor(rmax, 16));
      rmax = fmaxf(rmax, __shfl_xor(rmax, 32));
      const float mxn = fmaxf(mx[qt], rmax);
      const float msn = mxn * scale2;
      float sum = 0.f;
#pragma unroll
      for (int m = 0; m < 4; m++) {
        const float p0 = exp2f(__builtin_fmaf(st[m][qt][0], scale2, -msn));
        const float p1 = exp2f(__builtin_fmaf(st[m][qt][1], scale2, -msn));
        const float p2 = exp2f(__builtin_fmaf(st[m][qt][2], scale2, -msn));
        const float p3 = exp2f(__builtin_fmaf(st[m][qt][3], scale2, -msn));
        sum += (p0 + p1) + (p2 + p3);
        uint2 pk;
        pk.x = (unsigned)f2h(p0) | ((unsigned)f2h(p1) << 16);
        pk.y = (unsigned)f2h(p2) | ((unsigned)f2h(p3) << 16);
        *(uint2*)&Pw[(qt * 16 + ln) * 72 + m * 16 + quad * 4] = pk;
      }
      sum += __shfl_xor(sum, 16);
      sum += __shfl_xor(sum, 32);
      if (__any(rmax > mx[qt])) {
        const float alpha = exp2f(ms[qt] - msn);
        l[qt] = __builtin_fmaf(l[qt], alpha, sum);
#pragma unroll
        for (int dt = 0; dt < 4; dt++)
#pragma unroll
          for (int r = 0; r < 4; r++) o[dt][qt][r] *= alpha;
      } else {
        l[qt] += sum;
      }
      mx[qt] = mxn;
      ms[qt] = msn;
    }
    // wave-private write->read: LDS is in-order per wave; fence the compiler
    asm volatile("" ::: "memory");
    __builtin_amdgcn_sched_barrier(0);
    // O^T += V^T · P^T
#pragma unroll
    for (int c = 0; c < 2; c++) {
      h8 pb0 = *(const h8*)&Pw[(0 + ln) * 72 + c * 32 + quad * 8];
      h8 pb1 = *(const h8*)&Pw[(16 + ln) * 72 + c * 32 + quad * 8];
#pragma unroll
      for (int dt = 0; dt < 4; dt++) {
        o[dt][0] = __builtin_amdgcn_mfma_f32_16x16x32_f16(vf[dt][c], pb0, o[dt][0], 0, 0, 0);
        o[dt][1] = __builtin_amdgcn_mfma_f32_16x16x32_f16(vf[dt][c], pb1, o[dt][1], 0, 0, 0);
      }
    }
  }
  // epilogue: O^T/l -> Og[b][q][h*64+d], packed 8B stores
  const int b = bh >> 4, h = bh & 15;
#pragma unroll
  for (int qt = 0; qt < 2; qt++) {
    const float linv = __builtin_amdgcn_rcpf(l[qt]);
    const int q = q0 + qt * 16 + ln;
#pragma unroll
    for (int dt = 0; dt < 4; dt++) {
      uint2 pk;
      pk.x = (unsigned)f2h(o[dt][qt][0] * linv) | ((unsigned)f2h(o[dt][qt][1] * linv) << 16);
      pk.y = (unsigned)f2h(o[dt][qt][2] * linv) | ((unsigned)f2h(o[dt][qt][3] * linv) << 16);
      *(uint2*)&Og[((size_t)b * SQ_ + q) * D_ + h * DK_ + dt * 16 + quad * 4] = pk;
    }
  }
}

// ---------------------------------------------------------------- launch
extern "C" void kernel_launch(void* const* d_in, const int* in_sizes, int n_in,
                              void* d_out, int out_size, void* d_ws, size_t ws_size,
                              hipStream_t stream) {
  const float* query = (const float*)d_in[0];
  // d_in[1] = key : unused by the reference forward
  const float* value = (const float*)d_in[2];
  const float* R = (const float*)d_in[3];
  const float* Wq = (const float*)d_in[4];
  const float* bq = (const float*)d_in[5];
  const float* Wv = (const float*)d_in[6];
  const float* bv = (const float*)d_in[7];
  const float* Wr = (const float*)d_in[8];
  const float* br = (const float*)d_in[9];
  const float* W_h = (const float*)d_in[10];
  const float* Wo = (const float*)d_in[11];
  const float* bo = (const float*)d_in[12];
  float* out = (float*)d_out;

  char* ws = (char*)d_ws;
  const size_t MB = 1 << 20;
  u16* Xq = (u16*)(ws + 0 * MB);     // 8MB fp16 query
  u16* Xv = (u16*)(ws + 8 * MB);     // 8MB fp16 value
  u16* Xr = (u16*)(ws + 16 * MB);    // 8MB fp16 R
  u16* Wqb = (u16*)(ws + 24 * MB);   // 2MB
  u16* Wvb = (u16*)(ws + 26 * MB);   // 2MB
  u16* Wrb = (u16*)(ws + 28 * MB);   // 2MB
  u16* Wob = (u16*)(ws + 30 * MB);   // 2MB
  u16* Qb = (u16*)(ws + 32 * MB);    // 8MB fp16 (B,H,SQ,DK)
  u16* Vt = (u16*)(ws + 40 * MB);    // 8MB fp16 (B,H,DK,SK)  written directly by proj
  float* Rp = (float*)(ws + 48 * MB); // 16MB f32 (B,H,SK,DK)
  u16* Hs = (u16*)(ws + 64 * MB);    // 8MB fp16 (B,H,SK,DK)
  u16* Og = (u16*)(ws + 72 * MB);    // 8MB fp16 (B,SQ,D)  -> total 80MB

  rma_cast<<<dim3(2048, 1, 7), 256, 0, stream>>>(query, value, R, Wq, Wv, Wr, Wo,
                                                 Xq, Xv, Xr, Wqb, Wvb, Wrb, Wob);
  rma_proj_gemm<<<dim3(32, 8, 3), 256, 0, stream>>>(Xq, Xv, Xr, Wqb, Wvb, Wrb,
                                                    bq, bv, br, Qb, Vt, Rp);
  rma_recurrence<<<dim3(32), 64, 0, stream>>>(Rp, W_h, Hs);
  rma_flash<<<dim3(16, 32), 256, 0, stream>>>(Qb, Hs, Vt, Og);
  rma_final_gemm<<<dim3(64, 8), 256, 0, stream>>>(Og, Wob, bo, out);
}